// Round 1
// baseline (289.365 us; speedup 1.0000x reference)
//
#include <hip/hip_runtime.h>

// z_{t+1} = z_t @ K, T=256, B=256, D=512. out[b,t,d] = (z0 @ K^{t+1})[b,d], fp32.
//
// Strategy: chunked matrix powers, c=16.
//   Ladder (sequential, bf16x3 split precision, depth 9 launches):
//     K^1..K^16 by doubling; K^32, {K^48,K^64}, {K^80..K^128}, {K^144..K^240};
//     w_j = z0 @ K^{16j}, j=1..15 (one batched launch).
//   Parallel phase (one launch, plain bf16): out[16j+i-1] = w_j @ K^i  (2048 WGs).
//
// Every power is stored pre-split as 4 bf16 arrays per slot: [hiR | loR | hiT | loT]
// (row-major for A-operand staging, transposed for B-operand staging) so ALL GEMMs
// stage with 16B global_load_lds (m97-style). Workspace: 16 W slots + z0lo + 30
// power slots = 64.3 MB.

typedef unsigned short u16;
typedef unsigned int u32;
typedef __bf16 bf16x8 __attribute__((ext_vector_type(8)));
typedef float f32x4 __attribute__((ext_vector_type(4)));
typedef u16 u16x4 __attribute__((ext_vector_type(4)));

#define MAT 262144    /* 512*512 elems */
#define SLOT 1048576  /* 4*MAT u16 per power slot */
#define WSLOT 131072  /* 256*512 */

static_assert(sizeof(bf16x8) == 16, "bf16x8 must be 16B");

__device__ __forceinline__ u16 f2b(float f) {  // fp32 -> bf16 (RNE), bit-level
  u32 x = __float_as_uint(f);
  return (u16)((x + 0x7fffu + ((x >> 16) & 1u)) >> 16);
}
__device__ __forceinline__ float b2f(u16 u) { return __uint_as_float(((u32)u) << 16); }

// async global->LDS, 16B/lane. LDS dest is wave-uniform base + lane*16 (HW rule).
__device__ __forceinline__ void gll16(const void* g, void* l) {
  __builtin_amdgcn_global_load_lds((__attribute__((address_space(1))) void*)(void*)g,
                                   (__attribute__((address_space(3))) void*)l, 16, 0, 0);
}

// ---- prep: split K into slot0 (4 forms) via LDS transpose; split z0 -> W0(hi)+z0lo ----
__global__ __launch_bounds__(256) void prep_kernel(const float* __restrict__ Kc,
                                                   const float* __restrict__ z0,
                                                   u16* __restrict__ P,
                                                   u16* __restrict__ W0,
                                                   u16* __restrict__ z0lo) {
  __shared__ float tile[64][65];
  int tid = threadIdx.x, b = blockIdx.x;
  if (b < 64) {
    int by = b >> 3, bx = b & 7;
#pragma unroll 4
    for (int q = 0; q < 16; ++q) {
      int lin = q * 256 + tid;
      int r = lin >> 6, c = lin & 63;
      float v = Kc[(size_t)(by * 64 + r) * 512 + bx * 64 + c];
      tile[r][c] = v;
      u16 h = f2b(v), l = f2b(v - b2f(h));
      size_t o = (size_t)(by * 64 + r) * 512 + bx * 64 + c;
      P[o] = h;
      P[MAT + o] = l;
    }
    __syncthreads();
#pragma unroll 4
    for (int q = 0; q < 16; ++q) {
      int lin = q * 256 + tid;
      int c = lin >> 6, r = lin & 63;
      float v = tile[r][c];
      u16 h = f2b(v), l = f2b(v - b2f(h));
      size_t o = (size_t)(bx * 64 + c) * 512 + by * 64 + r;  // transposed, coalesced in r
      P[2 * MAT + o] = h;
      P[3 * MAT + o] = l;
    }
  } else {
    int idb = b - 64;  // 0..31 cover 131072 z0 elems
#pragma unroll 4
    for (int q = 0; q < 16; ++q) {
      int id = (idb * 16 + q) * 256 + tid;
      float v = z0[id];
      u16 h = f2b(v);
      W0[id] = h;
      z0lo[id] = f2b(v - b2f(h));
    }
  }
}

// ---- split-precision GEMM: C[M,512] = A[M,512] @ B[512,512], bf16x3 via MFMA ----
// A given as hi/lo row-major; B as hi/lo transposed ([n][k], lo at +MAT).
// wmode 0: epilogue writes full 4-form power slot; wmode 1: bf16-hi row-major only (W slot).
__global__ __launch_bounds__(256) void gemm_split(
    const u16* __restrict__ A0h, const u16* __restrict__ A0l, long Astr,
    const u16* __restrict__ B0h, long Bstr,
    u16* __restrict__ C0, long Cstr, int wmode) {
  __shared__ u16 Ah_s[64 * 32], Al_s[64 * 32], Bh_s[64 * 32], Bl_s[64 * 32];
  int z = blockIdx.z;
  const u16* Ah = A0h + (size_t)z * Astr;
  const u16* Al = A0l + (size_t)z * Astr;
  const u16* Bh = B0h + (size_t)z * Bstr;
  const u16* Bl = Bh + MAT;
  u16* C = C0 + (size_t)z * Cstr;
  int tid = threadIdx.x;
  int m0 = blockIdx.y * 64, n0 = blockIdx.x * 64;
  int lrow = tid >> 2, lc4 = tid & 3;
  size_t aoff = (size_t)(m0 + lrow) * 512 + lc4 * 8;
  size_t boff = (size_t)(n0 + lrow) * 512 + lc4 * 8;
  int wv = tid >> 6, lane = tid & 63;
  int lb = wv * 512;  // wave-uniform LDS base (elems)
  int wm = wv >> 1, wn = wv & 1, mrow = lane & 15, quad = lane >> 4;
  int aro = (wm * 32 + mrow) * 32 + quad * 8;
  int bro = (wn * 32 + mrow) * 32 + quad * 8;
  f32x4 acc[2][2] = {};
  for (int kt = 0; kt < 16; ++kt) {
    int ko = kt * 32;
    gll16(Ah + aoff + ko, Ah_s + lb);
    gll16(Al + aoff + ko, Al_s + lb);
    gll16(Bh + boff + ko, Bh_s + lb);
    gll16(Bl + boff + ko, Bl_s + lb);
    __syncthreads();
    bf16x8 ah[2], al[2], bh[2], bl[2];
#pragma unroll
    for (int t2 = 0; t2 < 2; ++t2) {
      ah[t2] = *(const bf16x8*)(Ah_s + aro + t2 * 16 * 32);
      al[t2] = *(const bf16x8*)(Al_s + aro + t2 * 16 * 32);
      bh[t2] = *(const bf16x8*)(Bh_s + bro + t2 * 16 * 32);
      bl[t2] = *(const bf16x8*)(Bl_s + bro + t2 * 16 * 32);
    }
#pragma unroll
    for (int mt = 0; mt < 2; ++mt)
#pragma unroll
      for (int nt = 0; nt < 2; ++nt) {
        acc[mt][nt] = __builtin_amdgcn_mfma_f32_16x16x32_bf16(ah[mt], bh[nt], acc[mt][nt], 0, 0, 0);
        acc[mt][nt] = __builtin_amdgcn_mfma_f32_16x16x32_bf16(al[mt], bh[nt], acc[mt][nt], 0, 0, 0);
        acc[mt][nt] = __builtin_amdgcn_mfma_f32_16x16x32_bf16(ah[mt], bl[nt], acc[mt][nt], 0, 0, 0);
      }
    __syncthreads();
  }
  // C/D layout: col = lane&15, row = quad*4 + reg  [m89/m91 verified]
#pragma unroll
  for (int mt = 0; mt < 2; ++mt)
#pragma unroll
    for (int nt = 0; nt < 2; ++nt) {
      int mb = m0 + wm * 32 + mt * 16 + quad * 4;
      int nn = n0 + wn * 32 + nt * 16 + mrow;
      if (wmode == 0) {
        u16x4 h4, l4;
#pragma unroll
        for (int r = 0; r < 4; ++r) {
          float v = acc[mt][nt][r];
          u16 h = f2b(v), l = f2b(v - b2f(h));
          C[(size_t)(mb + r) * 512 + nn] = h;
          C[MAT + (size_t)(mb + r) * 512 + nn] = l;
          h4[r] = h;
          l4[r] = l;
        }
        *(u16x4*)(C + 2 * MAT + (size_t)nn * 512 + mb) = h4;  // transposed, 8B packed
        *(u16x4*)(C + 3 * MAT + (size_t)nn * 512 + mb) = l4;
      } else {
#pragma unroll
        for (int r = 0; r < 4; ++r) C[(size_t)(mb + r) * 512 + nn] = f2b(acc[mt][nt][r]);
      }
    }
}

// ---- parallel phase: out[:, z, :] = W_{z>>4} @ K^{(z&15)+1}, plain bf16, 128x128 tiles ----
__global__ __launch_bounds__(256) void gemm_out(const u16* __restrict__ Wb,
                                                const u16* __restrict__ PT0,
                                                float* __restrict__ out) {
  __shared__ u16 As[128 * 32], Bs[128 * 32];
  int z = blockIdx.z;
  const u16* A = Wb + (size_t)(z >> 4) * WSLOT;
  const u16* Bt = PT0 + (size_t)(z & 15) * SLOT;
  int tid = threadIdx.x;
  int m0 = blockIdx.y * 128, n0 = blockIdx.x * 128;
  int lrow = tid >> 2, lc4 = tid & 3;
  size_t aoff = (size_t)(m0 + lrow) * 512 + lc4 * 8;
  size_t boff = (size_t)(n0 + lrow) * 512 + lc4 * 8;
  int wv = tid >> 6, lane = tid & 63;
  int lb = wv * 512;
  int wm = wv >> 1, wn = wv & 1, mrow = lane & 15, quad = lane >> 4;
  int aro = (wm * 64 + mrow) * 32 + quad * 8;
  int bro = (wn * 64 + mrow) * 32 + quad * 8;
  f32x4 acc[4][4] = {};
  for (int kt = 0; kt < 16; ++kt) {
    int ko = kt * 32;
    gll16(A + aoff + ko, As + lb);
    gll16(A + aoff + 64 * 512 + ko, As + 2048 + lb);
    gll16(Bt + boff + ko, Bs + lb);
    gll16(Bt + boff + 64 * 512 + ko, Bs + 2048 + lb);
    __syncthreads();
    bf16x8 a[4], b[4];
#pragma unroll
    for (int t4 = 0; t4 < 4; ++t4) {
      a[t4] = *(const bf16x8*)(As + aro + t4 * 16 * 32);
      b[t4] = *(const bf16x8*)(Bs + bro + t4 * 16 * 32);
    }
#pragma unroll
    for (int mt = 0; mt < 4; ++mt)
#pragma unroll
      for (int nt = 0; nt < 4; ++nt)
        acc[mt][nt] = __builtin_amdgcn_mfma_f32_16x16x32_bf16(a[mt], b[nt], acc[mt][nt], 0, 0, 0);
    __syncthreads();
  }
#pragma unroll
  for (int mt = 0; mt < 4; ++mt)
#pragma unroll
    for (int nt = 0; nt < 4; ++nt) {
      int gb = m0 + wm * 64 + mt * 16 + quad * 4;
      int gd = n0 + wn * 64 + nt * 16 + mrow;
#pragma unroll
      for (int r = 0; r < 4; ++r)
        out[((size_t)(gb + r) * 256 + z) * 512 + gd] = acc[mt][nt][r];
    }
}

extern "C" void kernel_launch(void* const* d_in, const int* in_sizes, int n_in,
                              void* d_out, int out_size, void* d_ws, size_t ws_size,
                              hipStream_t stream) {
  const float* z0 = (const float*)d_in[0];
  const float* Kc = (const float*)d_in[1];
  float* out = (float*)d_out;
  // ws layout (u16): W[16*WSLOT] | z0lo[WSLOT] | P[30*SLOT]  == 64.3 MB total
  u16* W = (u16*)d_ws;
  u16* z0l = W + 16 * WSLOT;
  u16* P = z0l + WSLOT;
  auto S = [&](int s) { return P + (size_t)s * SLOT; };  // slot s: 0..15 = K^{s+1}; 16..29 = K^{16(s-14)}
  dim3 blk(256);

  prep_kernel<<<96, blk, 0, stream>>>(Kc, z0, P, W, z0l);
  // small-power doubling ladder: K^2; K^{3,4}; K^{5..8}; K^{9..16}
  gemm_split<<<dim3(8, 8, 1), blk, 0, stream>>>(S(0), S(0) + MAT, 0, S(0) + 2 * MAT, 0, S(1), 0, 0);
  gemm_split<<<dim3(8, 8, 2), blk, 0, stream>>>(S(0), S(0) + MAT, SLOT, S(1) + 2 * MAT, 0, S(2), SLOT, 0);
  gemm_split<<<dim3(8, 8, 4), blk, 0, stream>>>(S(0), S(0) + MAT, SLOT, S(3) + 2 * MAT, 0, S(4), SLOT, 0);
  gemm_split<<<dim3(8, 8, 8), blk, 0, stream>>>(S(0), S(0) + MAT, SLOT, S(7) + 2 * MAT, 0, S(8), SLOT, 0);
  // big powers: K^32; {K^48,K^64}; {K^80..K^128}; {K^144..K^240}
  gemm_split<<<dim3(8, 8, 1), blk, 0, stream>>>(S(15), S(15) + MAT, 0, S(15) + 2 * MAT, 0, S(16), 0, 0);
  gemm_split<<<dim3(8, 8, 2), blk, 0, stream>>>(S(16), S(16) + MAT, 0, S(15) + 2 * MAT, SLOT, S(17), SLOT, 0);
  gemm_split<<<dim3(8, 8, 4), blk, 0, stream>>>(S(18), S(18) + MAT, 0, S(15) + 2 * MAT, SLOT, S(19), SLOT, 0);
  gemm_split<<<dim3(8, 8, 7), blk, 0, stream>>>(S(22), S(22) + MAT, 0, S(15) + 2 * MAT, SLOT, S(23), SLOT, 0);
  // w_j = z0 @ K^{16j}, j=1..15 (one batched launch, writes bf16-hi W slots)
  gemm_split<<<dim3(8, 4, 15), blk, 0, stream>>>(W, z0l, 0, S(15) + 2 * MAT, SLOT, W + WSLOT, WSLOT, 1);
  // parallel phase: all 256 timesteps
  gemm_out<<<dim3(4, 2, 256), blk, 0, stream>>>(W, P + 2 * MAT, out);
}